// Round 7
// baseline (7631.133 us; speedup 1.0000x reference)
//
#include <hip/hip_runtime.h>

// Problem constants
#define B_ 2048
#define S_ 512
#define I_ 256
#define F_ 256
#define NG 8            // partial-groups for the W2 fold
#define TCHUNKS 16      // k1 blocks per batch (S_/32)

// Workspace layout (in floats)
#define OFF_W    0                       // w[B,F]   (hidden @ W1^T)
#define OFF_SW   (OFF_W + B_*F_)         // Sw[B]    (row sums of w)
#define OFF_U    (OFF_SW + B_)           // u[B,S]
#define OFF_P    (OFF_U + B_*S_)         // p[B,S]
#define OFF_RP   (OFF_P + B_*S_)         // rp[NG][512] partial r = Wfc@W2
#define OFF_CNT  (OFF_RP + NG*512)       // cnt[B] ints (ticket counters)
// total ~10.5 MB + 8 KB

// ---------------------------------------------------------------------------
// k_pre: blocks 0..511  : w[b,f] = hidden[b,:].W1[f,:], Sw[b] (4 batches/block)
//        blocks 512..519: partial fold rp[g][j] + zero the ticket counters
__global__ __launch_bounds__(256) void k_pre(
    const float* __restrict__ hidden, const float* __restrict__ W1,
    const float* __restrict__ W2, const float* __restrict__ Wfc,
    float* __restrict__ ws, int* __restrict__ cnt) {
  const int tid = threadIdx.x;

  if (blockIdx.x >= B_ / 4) {
    const int g = blockIdx.x - B_ / 4;
    cnt[g * 256 + tid] = 0;   // re-zero tickets every launch (replay-safe)
    float acc0 = 0.f, acc1 = 0.f;
#pragma unroll 8
    for (int ii = 0; ii < 32; ++ii) {
      const int i = g * 32 + ii;
      const float f = Wfc[i];
      acc0 += f * W2[(size_t)i * (I_ + F_) + tid];
      acc1 += f * W2[(size_t)i * (I_ + F_) + tid + 256];
    }
    ws[OFF_RP + g * 512 + tid] = acc0;        // r_h partial
    ws[OFF_RP + g * 512 + 256 + tid] = acc1;  // r_v partial
    return;
  }

  __shared__ float h[4][I_];
  __shared__ float red[256];
  const int b0 = blockIdx.x * 4;
#pragma unroll
  for (int k = 0; k < 4; ++k) h[k][tid] = hidden[(size_t)(b0 + k) * I_ + tid];
  __syncthreads();

  const int f = tid;
  const float4* wrow = (const float4*)(W1 + (size_t)f * I_);
  float acc[4] = {0.f, 0.f, 0.f, 0.f};
#pragma unroll 4
  for (int iq = 0; iq < I_ / 4; ++iq) {
    const float4 v = wrow[iq];
    const int i = 4 * iq;
#pragma unroll
    for (int k = 0; k < 4; ++k)
      acc[k] += v.x * h[k][i] + v.y * h[k][i + 1] + v.z * h[k][i + 2] + v.w * h[k][i + 3];
  }
#pragma unroll
  for (int k = 0; k < 4; ++k) ws[OFF_W + (size_t)(b0 + k) * F_ + f] = acc[k];

#pragma unroll
  for (int k = 0; k < 4; ++k) {
    red[tid] = acc[k];
    __syncthreads();
    for (int s = 128; s > 0; s >>= 1) { if (tid < s) red[tid] += red[tid + s]; __syncthreads(); }
    if (tid == 0) ws[OFF_SW + b0 + k] = red[0];
    __syncthreads();
  }
}

// ---------------------------------------------------------------------------
// k1_fused: R5's streaming body (byte-identical math) + last-block epilogue.
// Streaming: u[b,t] = inp[b,t,:].w[b,:], p[b,t] = inp[b,t,:].r_v[:]
// Epilogue (ticket 15): R5-k2 math for one batch from LDS-staged u,p.
__global__ __launch_bounds__(256) void k1_fused(
    const float* __restrict__ inp, const float* __restrict__ Wc,
    const float* __restrict__ bc, const float* __restrict__ b2,
    const float* __restrict__ Wfc, const float* __restrict__ bfc,
    const float* __restrict__ hidden,
    const float* __restrict__ wsw, const float* __restrict__ wsSw,
    const float* __restrict__ wsrp,
    float* __restrict__ wsu, float* __restrict__ wsp,
    int* __restrict__ cnt, float* __restrict__ out) {
  const int ROWS = 32;
  const int b = blockIdx.y;
  const int t0 = blockIdx.x * ROWS;
  const int tid = threadIdx.x;
  const int lane = tid & 63;
  const int wid = tid >> 6;

  __shared__ float rv_lds[F_];
  float rvr = 0.f;
#pragma unroll
  for (int g = 0; g < NG; ++g) rvr += wsrp[g * 512 + 256 + tid];
  rv_lds[tid] = rvr;
  __syncthreads();

  const float4 w4  = ((const float4*)(wsw + (size_t)b * F_))[lane];
  const float4 rv4 = ((const float4*)rv_lds)[lane];
  const float* base = inp + ((size_t)b * S_ + t0) * I_;
  float* uo = wsu + (size_t)b * S_ + t0;
  float* po = wsp + (size_t)b * S_ + t0;

#pragma unroll
  for (int rr = 0; rr < ROWS / 4; ++rr) {
    const int row = wid + 4 * rr;
    const float4 in4 = ((const float4*)(base + (size_t)row * I_))[lane];
    float du = in4.x * w4.x + in4.y * w4.y + in4.z * w4.z + in4.w * w4.w;
    float dp = in4.x * rv4.x + in4.y * rv4.y + in4.z * rv4.z + in4.w * rv4.w;
#pragma unroll
    for (int m = 32; m >= 1; m >>= 1) {
      du += __shfl_xor(du, m, 64);
      dp += __shfl_xor(dp, m, 64);
    }
    if (lane == 0) { uo[row] = du; po[row] = dp; }
  }

  // ---- ticket: last block of batch b runs the epilogue ----
  __threadfence();                       // release: make u,p visible device-wide
  __shared__ int go_s;
  if (tid == 0) go_s = (atomicAdd(&cnt[b], 1) == TCHUNKS - 1);
  __syncthreads();
  if (!go_s) return;
  __threadfence();                       // acquire: invalidate stale cache lines

  __shared__ float u_l[S_], p_l[S_];
  __shared__ float redA[4], redB[4], redC[4];
#pragma unroll
  for (int q = 0; q < 2; ++q) {
    u_l[q * 256 + tid] = wsu[(size_t)b * S_ + q * 256 + tid];
    p_l[q * 256 + tid] = wsp[(size_t)b * S_ + q * 256 + tid];
  }

  float rh = 0.f;
#pragma unroll
  for (int g = 0; g < NG; ++g) rh += wsrp[g * 512 + tid];

  float t0r = rv_lds[tid], t1r = Wfc[tid] * b2[tid];
#pragma unroll
  for (int m = 32; m >= 1; m >>= 1) {
    t0r += __shfl_xor(t0r, m, 64);
    t1r += __shfl_xor(t1r, m, 64);
  }
  if (lane == 0) { redA[wid] = t0r; redB[wid] = t1r; }
  __syncthreads();
  const float R  = redA[0] + redA[1] + redA[2] + redA[3];
  const float c0 = redB[0] + redB[1] + redB[2] + redB[3] + bfc[0];
  const float Sw = wsSw[b];

  const float4* wrow = (const float4*)(Wc + (size_t)tid * S_);
  float ssum = 0.f, qsum = 0.f;
#pragma unroll 4
  for (int tq = 0; tq < S_ / 4; ++tq) {
    const float4 v = wrow[tq];
    const float4 uu = ((const float4*)u_l)[tq];
    const float4 pp = ((const float4*)p_l)[tq];
    ssum += v.x * uu.x + v.y * uu.y + v.z * uu.z + v.w * uu.w;
    qsum += v.x * pp.x + v.y * pp.y + v.z * pp.z + v.w * pp.w;
  }
  const float bcx = bc[tid];
  const float s = ssum + bcx * Sw;
  const float a = 1.f / (1.f + expf(-s));
  float partial = a * (qsum + bcx * R) + rh * hidden[(size_t)b * I_ + tid];
#pragma unroll
  for (int m = 32; m >= 1; m >>= 1) partial += __shfl_xor(partial, m, 64);
  if (lane == 0) redC[wid] = partial;
  __syncthreads();
  if (tid == 0) out[b] = redC[0] + redC[1] + redC[2] + redC[3] + c0;
}

// ---------------------------------------------------------------------------
extern "C" void kernel_launch(void* const* d_in, const int* in_sizes, int n_in,
                              void* d_out, int out_size, void* d_ws, size_t ws_size,
                              hipStream_t stream) {
  (void)in_sizes; (void)n_in; (void)out_size; (void)ws_size;
  const float* hidden = (const float*)d_in[0];
  const float* inp    = (const float*)d_in[1];
  const float* W1     = (const float*)d_in[2];
  const float* Wc     = (const float*)d_in[3];
  const float* bc     = (const float*)d_in[4];
  const float* W2     = (const float*)d_in[5];
  const float* b2     = (const float*)d_in[6];
  const float* Wfc    = (const float*)d_in[7];
  const float* bfc    = (const float*)d_in[8];
  float* out = (float*)d_out;
  float* ws  = (float*)d_ws;
  int* cnt   = (int*)(ws + OFF_CNT);

  hipLaunchKernelGGL(k_pre, dim3(B_ / 4 + NG), dim3(256), 0, stream,
                     hidden, W1, W2, Wfc, ws, cnt);
  hipLaunchKernelGGL(k1_fused, dim3(TCHUNKS, B_), dim3(256), 0, stream,
                     inp, Wc, bc, b2, Wfc, bfc, hidden,
                     ws + OFF_W, ws + OFF_SW, ws + OFF_RP,
                     ws + OFF_U, ws + OFF_P, cnt, out);
}

// Round 8
// 266.347 us; speedup vs baseline: 28.6511x; 28.6511x over previous
//
#include <hip/hip_runtime.h>

// Problem constants
#define B_ 2048
#define S_ 512
#define I_ 256
#define F_ 256
#define NG 8   // partial-groups for the W2 fold

// Workspace layout (in floats)
#define OFF_W    0                       // w[B,F]   (hidden @ W1^T)
#define OFF_SW   (OFF_W + B_*F_)         // Sw[B]    (row sums of w)
#define OFF_U    (OFF_SW + B_)           // u[B,S]
#define OFF_P    (OFF_U + B_*S_)         // p[B,S]
#define OFF_RP   (OFF_P + B_*S_)         // rp[NG][512] partial r = Wfc@W2
// total floats = OFF_RP + NG*512 = 2,628,608 (~10.5 MB)

// ---------------------------------------------------------------------------
// k_pre: blocks 0..511  : w[b,f] = hidden[b,:].W1[f,:], Sw[b] (4 batches/block)
//        blocks 512..519: partial fold rp[g][j] = sum_{i in g's 32} Wfc[i]*W2[i,j]
// (byte-identical to R5)
__global__ __launch_bounds__(256) void k_pre(
    const float* __restrict__ hidden, const float* __restrict__ W1,
    const float* __restrict__ W2, const float* __restrict__ Wfc,
    float* __restrict__ ws) {
  const int tid = threadIdx.x;

  if (blockIdx.x >= B_ / 4) {
    const int g = blockIdx.x - B_ / 4;
    float acc0 = 0.f, acc1 = 0.f;
#pragma unroll 8
    for (int ii = 0; ii < 32; ++ii) {
      const int i = g * 32 + ii;
      const float f = Wfc[i];
      acc0 += f * W2[(size_t)i * (I_ + F_) + tid];
      acc1 += f * W2[(size_t)i * (I_ + F_) + tid + 256];
    }
    ws[OFF_RP + g * 512 + tid] = acc0;        // r_h partial
    ws[OFF_RP + g * 512 + 256 + tid] = acc1;  // r_v partial
    return;
  }

  __shared__ float h[4][I_];
  __shared__ float red[256];
  const int b0 = blockIdx.x * 4;
#pragma unroll
  for (int k = 0; k < 4; ++k) h[k][tid] = hidden[(size_t)(b0 + k) * I_ + tid];
  __syncthreads();

  const int f = tid;
  const float4* wrow = (const float4*)(W1 + (size_t)f * I_);
  float acc[4] = {0.f, 0.f, 0.f, 0.f};
#pragma unroll 4
  for (int iq = 0; iq < I_ / 4; ++iq) {
    const float4 v = wrow[iq];
    const int i = 4 * iq;
#pragma unroll
    for (int k = 0; k < 4; ++k)
      acc[k] += v.x * h[k][i] + v.y * h[k][i + 1] + v.z * h[k][i + 2] + v.w * h[k][i + 3];
  }
#pragma unroll
  for (int k = 0; k < 4; ++k) ws[OFF_W + (size_t)(b0 + k) * F_ + f] = acc[k];

#pragma unroll
  for (int k = 0; k < 4; ++k) {
    red[tid] = acc[k];
    __syncthreads();
    for (int s = 128; s > 0; s >>= 1) { if (tid < s) red[tid] += red[tid + s]; __syncthreads(); }
    if (tid == 0) ws[OFF_SW + b0 + k] = red[0];
    __syncthreads();
  }
}

// ---------------------------------------------------------------------------
// DPP 64-lane dual sum: row_shr 1/2/4/8 then row_bcast:15, row_bcast:31.
// All VALU (no LDS pipe). Totals land in lane 63. bound_ctrl=true -> OOB reads 0.
__device__ __forceinline__ void dpp_sum64_dual(float& xu, float& xp) {
  int iu = __builtin_bit_cast(int, xu);
  int ip = __builtin_bit_cast(int, xp);
#define DPP_STEP(ctrl)                                                         \
  {                                                                            \
    int tu = __builtin_amdgcn_update_dpp(0, iu, (ctrl), 0xf, 0xf, true);       \
    int tp = __builtin_amdgcn_update_dpp(0, ip, (ctrl), 0xf, 0xf, true);       \
    iu = __builtin_bit_cast(int, __builtin_bit_cast(float, iu) +               \
                                     __builtin_bit_cast(float, tu));           \
    ip = __builtin_bit_cast(int, __builtin_bit_cast(float, ip) +               \
                                     __builtin_bit_cast(float, tp));           \
  }
  DPP_STEP(0x111)  // row_shr:1
  DPP_STEP(0x112)  // row_shr:2
  DPP_STEP(0x114)  // row_shr:4
  DPP_STEP(0x118)  // row_shr:8  -> lane 15 of each row16 = row sum
  DPP_STEP(0x142)  // row_bcast:15 -> lane31 = sum(0..31), lane63 = sum(32..63)
  DPP_STEP(0x143)  // row_bcast:31 -> lane63 = sum(0..63)
#undef DPP_STEP
  xu = __builtin_bit_cast(float, iu);
  xp = __builtin_bit_cast(float, ip);
}

// ---------------------------------------------------------------------------
// K1: single pass over inp (1 GB) — R5 shape, reduction moved to DPP (VALU).
//   u[b,t] = inp[b,t,:].w[b,:]   p[b,t] = inp[b,t,:].r_v[:]
__global__ __launch_bounds__(256) void k1_scan(
    const float* __restrict__ inp, const float* __restrict__ wsw,
    const float* __restrict__ wsrp,
    float* __restrict__ wsu, float* __restrict__ wsp) {
  const int ROWS = 32;
  const int b = blockIdx.y;
  const int t0 = blockIdx.x * ROWS;
  const int tid = threadIdx.x;
  const int lane = tid & 63;
  const int wid = tid >> 6;

  __shared__ float rv_lds[F_];
  float rv = 0.f;
#pragma unroll
  for (int g = 0; g < NG; ++g) rv += wsrp[g * 512 + 256 + tid];
  rv_lds[tid] = rv;
  __syncthreads();

  const float4 w4  = ((const float4*)(wsw + (size_t)b * F_))[lane];
  const float4 rv4 = ((const float4*)rv_lds)[lane];
  const float* base = inp + ((size_t)b * S_ + t0) * I_;
  float* uo = wsu + (size_t)b * S_ + t0;
  float* po = wsp + (size_t)b * S_ + t0;

#pragma unroll
  for (int rr = 0; rr < ROWS / 4; ++rr) {
    const int row = wid + 4 * rr;
    const float4 in4 = ((const float4*)(base + (size_t)row * I_))[lane];
    float du = in4.x * w4.x + in4.y * w4.y + in4.z * w4.z + in4.w * w4.w;
    float dp = in4.x * rv4.x + in4.y * rv4.y + in4.z * rv4.z + in4.w * rv4.w;
    dpp_sum64_dual(du, dp);
    if (lane == 63) { uo[row] = du; po[row] = dp; }
  }
}

// ---------------------------------------------------------------------------
// K2: per-batch epilogue — byte-identical to R5.
__global__ __launch_bounds__(256) void k2_epilogue(
    const float* __restrict__ Wc, const float* __restrict__ bc,
    const float* __restrict__ b2, const float* __restrict__ Wfc,
    const float* __restrict__ bfc, const float* __restrict__ hidden,
    const float* __restrict__ wsu, const float* __restrict__ wsp,
    const float* __restrict__ wsSw, const float* __restrict__ wsrp,
    float* __restrict__ out) {
  const int b0 = blockIdx.x * 4;
  const int tid = threadIdx.x;
  const int lane = tid & 63;
  const int wid = tid >> 6;
  __shared__ float u[4][S_];
  __shared__ float p[4][S_];
  __shared__ float redA[4], redB[4];
  __shared__ float wred[4][4];

  // fold r partials
  float rh = 0.f, rv = 0.f;
#pragma unroll
  for (int g = 0; g < NG; ++g) {
    rh += wsrp[g * 512 + tid];
    rv += wsrp[g * 512 + 256 + tid];
  }
  // R = sum(r_v); c0 = Wfc.b2 + bfc
  float t0 = rv, t1 = Wfc[tid] * b2[tid];
#pragma unroll
  for (int m = 32; m >= 1; m >>= 1) {
    t0 += __shfl_xor(t0, m, 64);
    t1 += __shfl_xor(t1, m, 64);
  }
  if (lane == 0) { redA[wid] = t0; redB[wid] = t1; }

#pragma unroll
  for (int k = 0; k < 4; ++k) {
    u[k][tid]       = wsu[(size_t)(b0 + k) * S_ + tid];
    u[k][tid + 256] = wsu[(size_t)(b0 + k) * S_ + tid + 256];
    p[k][tid]       = wsp[(size_t)(b0 + k) * S_ + tid];
    p[k][tid + 256] = wsp[(size_t)(b0 + k) * S_ + tid + 256];
  }
  __syncthreads();

  const float R  = redA[0] + redA[1] + redA[2] + redA[3];
  const float c0 = redB[0] + redB[1] + redB[2] + redB[3] + bfc[0];

  const int x = tid;
  const float4* wrow = (const float4*)(Wc + (size_t)x * S_);
  float ss[4] = {0.f, 0.f, 0.f, 0.f};
  float qs[4] = {0.f, 0.f, 0.f, 0.f};
#pragma unroll 4
  for (int tq = 0; tq < S_ / 4; ++tq) {
    const float4 v = wrow[tq];
    const int t = 4 * tq;
#pragma unroll
    for (int k = 0; k < 4; ++k) {
      ss[k] += v.x * u[k][t] + v.y * u[k][t + 1] + v.z * u[k][t + 2] + v.w * u[k][t + 3];
      qs[k] += v.x * p[k][t] + v.y * p[k][t + 1] + v.z * p[k][t + 2] + v.w * p[k][t + 3];
    }
  }

  const float bcx = bc[x];
#pragma unroll
  for (int k = 0; k < 4; ++k) {
    const float Sw = wsSw[b0 + k];
    const float s = ss[k] + bcx * Sw;
    const float a = 1.f / (1.f + expf(-s));
    float partial = a * (qs[k] + bcx * R) + rh * hidden[(size_t)(b0 + k) * I_ + x];
#pragma unroll
    for (int m = 32; m >= 1; m >>= 1) partial += __shfl_xor(partial, m, 64);
    if (lane == 0) wred[k][wid] = partial;
  }
  __syncthreads();
  if (tid < 4)
    out[b0 + tid] = wred[tid][0] + wred[tid][1] + wred[tid][2] + wred[tid][3] + c0;
}

// ---------------------------------------------------------------------------
extern "C" void kernel_launch(void* const* d_in, const int* in_sizes, int n_in,
                              void* d_out, int out_size, void* d_ws, size_t ws_size,
                              hipStream_t stream) {
  (void)in_sizes; (void)n_in; (void)out_size; (void)ws_size;
  const float* hidden = (const float*)d_in[0];
  const float* inp    = (const float*)d_in[1];
  const float* W1     = (const float*)d_in[2];
  const float* Wc     = (const float*)d_in[3];
  const float* bc     = (const float*)d_in[4];
  const float* W2     = (const float*)d_in[5];
  const float* b2     = (const float*)d_in[6];
  const float* Wfc    = (const float*)d_in[7];
  const float* bfc    = (const float*)d_in[8];
  float* out = (float*)d_out;
  float* ws  = (float*)d_ws;

  hipLaunchKernelGGL(k_pre, dim3(B_ / 4 + NG), dim3(256), 0, stream,
                     hidden, W1, W2, Wfc, ws);
  hipLaunchKernelGGL(k1_scan, dim3(S_ / 32, B_), dim3(256), 0, stream,
                     inp, ws + OFF_W, ws + OFF_RP, ws + OFF_U, ws + OFF_P);
  hipLaunchKernelGGL(k2_epilogue, dim3(B_ / 4), dim3(256), 0, stream,
                     Wc, bc, b2, Wfc, bfc, hidden,
                     ws + OFF_U, ws + OFF_P, ws + OFF_SW, ws + OFF_RP, out);
}

// Round 9
// 264.225 us; speedup vs baseline: 28.8812x; 1.0080x over previous
//
#include <hip/hip_runtime.h>

// Problem constants
#define B_ 2048
#define S_ 512
#define I_ 256
#define F_ 256
#define NG 8   // partial-groups for the W2 fold

// ---------------- workspace layout (floats) ----------------
#define OFF_W    0                        // w[B,F]
#define OFF_SW   (OFF_W + B_*F_)          // Sw[B]                  (524288)
#define OFF_RP   (OFF_SW + B_)            // rp[NG][512]            (526336)
#define OFF_RH   (OFF_RP + NG*512)        // rh[256]                (530432)
#define OFF_RV   (OFF_RH + 256)           // rv[256]                (530688)
#define OFF_SC   (OFF_RV + 256)           // sc[2]: R, c0           (530944)
#define OFF_WCT  531456                   // WcT[512][256]          (2 MB region)
#define OFF_PS   (OFF_WCT + S_*F_)        // ps[B][NCH][256]        (662528)
// fused path: pq follows ps (size B*NCH*256 each)
// classic fallback reuses [OFF_WCT ...] for u,p:
#define OFF_U2   OFF_WCT                  // u[B,S]
#define OFF_P2   (OFF_U2 + B_*S_)         // p[B,S]  (end = 2,628,608 floats = 10.5 MB)

// ---------------------------------------------------------------------------
// k_pre: blocks [0,512)  : w[b,f] = hidden[b,:].W1[f,:], Sw[b]
//        blocks [512,520): rp partial fold of r = Wfc@W2
//        blocks [520,552): WcT[t][x] = Wc[x][t]  (64x64 LDS tiles)
__global__ __launch_bounds__(256) void k_pre(
    const float* __restrict__ hidden, const float* __restrict__ W1,
    const float* __restrict__ W2, const float* __restrict__ Wfc,
    const float* __restrict__ Wc, float* __restrict__ ws) {
  const int tid = threadIdx.x;

  if (blockIdx.x >= B_ / 4 + NG) {
    // ---- transpose Wc -> WcT ----
    __shared__ float tile[64][65];
    const int tt = blockIdx.x - (B_ / 4 + NG);
    const int x0 = (tt & 3) * 64;
    const int t0 = (tt >> 2) * 64;
    const int col = tid & 63;
    const int wid = tid >> 6;
#pragma unroll
    for (int r = 0; r < 16; ++r) {
      const int row = r * 4 + wid;
      tile[row][col] = Wc[(size_t)(x0 + row) * S_ + t0 + col];
    }
    __syncthreads();
#pragma unroll
    for (int r = 0; r < 16; ++r) {
      const int trow = r * 4 + wid;
      ws[OFF_WCT + (size_t)(t0 + trow) * F_ + x0 + col] = tile[col][trow];
    }
    return;
  }

  if (blockIdx.x >= B_ / 4) {
    const int g = blockIdx.x - B_ / 4;
    float acc0 = 0.f, acc1 = 0.f;
#pragma unroll 8
    for (int ii = 0; ii < 32; ++ii) {
      const int i = g * 32 + ii;
      const float f = Wfc[i];
      acc0 += f * W2[(size_t)i * (I_ + F_) + tid];
      acc1 += f * W2[(size_t)i * (I_ + F_) + tid + 256];
    }
    ws[OFF_RP + g * 512 + tid] = acc0;        // r_h partial
    ws[OFF_RP + g * 512 + 256 + tid] = acc1;  // r_v partial
    return;
  }

  __shared__ float h[4][I_];
  __shared__ float red[256];
  const int b0 = blockIdx.x * 4;
#pragma unroll
  for (int k = 0; k < 4; ++k) h[k][tid] = hidden[(size_t)(b0 + k) * I_ + tid];
  __syncthreads();

  const int f = tid;
  const float4* wrow = (const float4*)(W1 + (size_t)f * I_);
  float acc[4] = {0.f, 0.f, 0.f, 0.f};
#pragma unroll 4
  for (int iq = 0; iq < I_ / 4; ++iq) {
    const float4 v = wrow[iq];
    const int i = 4 * iq;
#pragma unroll
    for (int k = 0; k < 4; ++k)
      acc[k] += v.x * h[k][i] + v.y * h[k][i + 1] + v.z * h[k][i + 2] + v.w * h[k][i + 3];
  }
#pragma unroll
  for (int k = 0; k < 4; ++k) ws[OFF_W + (size_t)(b0 + k) * F_ + f] = acc[k];

#pragma unroll
  for (int k = 0; k < 4; ++k) {
    red[tid] = acc[k];
    __syncthreads();
    for (int s = 128; s > 0; s >>= 1) { if (tid < s) red[tid] += red[tid + s]; __syncthreads(); }
    if (tid == 0) ws[OFF_SW + b0 + k] = red[0];
    __syncthreads();
  }
}

// ---------------------------------------------------------------------------
// k_mid: one block. rh[x], rv[x] folded from partials; R = sum(rv);
// c0 = Wfc.b2 + bfc.
__global__ __launch_bounds__(256) void k_mid(
    const float* __restrict__ Wfc, const float* __restrict__ b2,
    const float* __restrict__ bfc, float* __restrict__ ws) {
  const int tid = threadIdx.x;
  const int lane = tid & 63;
  const int wid = tid >> 6;
  __shared__ float redA[4], redB[4];

  float rh = 0.f, rv = 0.f;
#pragma unroll
  for (int g = 0; g < NG; ++g) {
    rh += ws[OFF_RP + g * 512 + tid];
    rv += ws[OFF_RP + g * 512 + 256 + tid];
  }
  ws[OFF_RH + tid] = rh;
  ws[OFF_RV + tid] = rv;

  float t0 = rv, t1 = Wfc[tid] * b2[tid];
#pragma unroll
  for (int m = 32; m >= 1; m >>= 1) {
    t0 += __shfl_xor(t0, m, 64);
    t1 += __shfl_xor(t1, m, 64);
  }
  if (lane == 0) { redA[wid] = t0; redB[wid] = t1; }
  __syncthreads();
  if (tid == 0) {
    ws[OFF_SC + 0] = redA[0] + redA[1] + redA[2] + redA[3];           // R
    ws[OFF_SC + 1] = redB[0] + redB[1] + redB[2] + redB[3] + bfc[0];  // c0
  }
}

// ---------------------------------------------------------------------------
// DPP 64-lane dual sum (R8-proven). Totals land in lane 63.
__device__ __forceinline__ void dpp_sum64_dual(float& xu, float& xp) {
  int iu = __builtin_bit_cast(int, xu);
  int ip = __builtin_bit_cast(int, xp);
#define DPP_STEP(ctrl)                                                         \
  {                                                                            \
    int tu = __builtin_amdgcn_update_dpp(0, iu, (ctrl), 0xf, 0xf, true);       \
    int tp = __builtin_amdgcn_update_dpp(0, ip, (ctrl), 0xf, 0xf, true);       \
    iu = __builtin_bit_cast(int, __builtin_bit_cast(float, iu) +               \
                                     __builtin_bit_cast(float, tu));           \
    ip = __builtin_bit_cast(int, __builtin_bit_cast(float, ip) +               \
                                     __builtin_bit_cast(float, tp));           \
  }
  DPP_STEP(0x111) DPP_STEP(0x112) DPP_STEP(0x114) DPP_STEP(0x118)
  DPP_STEP(0x142) DPP_STEP(0x143)
#undef DPP_STEP
  xu = __builtin_bit_cast(float, iu);
  xp = __builtin_bit_cast(float, ip);
}

// ---------------------------------------------------------------------------
// k1_fused<NCH>: grid (NCH, B). Block = chunk of ROWS=512/NCH t's for batch b.
// Phase A: u[t],p[t] for chunk (R8 streaming body) -> LDS.
// Phase B: partial contraction ps[x] = sum_t WcT[t][x]*u[t] (coalesced),
//          pq likewise; write coalesced partials.
template <int NCH>
__global__ __launch_bounds__(256) void k1_fused(
    const float* __restrict__ inp, const float* __restrict__ wsw,
    const float* __restrict__ wsrv, const float* __restrict__ wct,
    float* __restrict__ ps, float* __restrict__ pq) {
  constexpr int ROWS = S_ / NCH;
  const int b = blockIdx.y;
  const int cx = blockIdx.x;
  const int t0 = cx * ROWS;
  const int tid = threadIdx.x;
  const int lane = tid & 63;
  const int wid = tid >> 6;

  __shared__ __align__(16) float u_l[ROWS];
  __shared__ __align__(16) float p_l[ROWS];

  const float4 w4  = ((const float4*)(wsw + (size_t)b * F_))[lane];
  const float4 rv4 = ((const float4*)wsrv)[lane];
  const float* base = inp + ((size_t)b * S_ + t0) * I_;

#pragma unroll 4
  for (int rr = 0; rr < ROWS / 4; ++rr) {
    const int row = rr * 4 + wid;
    const float4 in4 = ((const float4*)(base + (size_t)row * I_))[lane];
    float du = in4.x * w4.x + in4.y * w4.y + in4.z * w4.z + in4.w * w4.w;
    float dp = in4.x * rv4.x + in4.y * rv4.y + in4.z * rv4.z + in4.w * rv4.w;
    dpp_sum64_dual(du, dp);
    if (lane == 63) { u_l[row] = du; p_l[row] = dp; }
  }
  __syncthreads();

  // Phase B: thread x = tid
  const float* wcol = wct + t0 * F_ + tid;
  float ss = 0.f, qq = 0.f;
#pragma unroll 4
  for (int jq = 0; jq < ROWS / 4; ++jq) {
    const float4 u4 = *(const float4*)&u_l[jq * 4];
    const float4 p4 = *(const float4*)&p_l[jq * 4];
    const float w0 = wcol[(size_t)(jq * 4 + 0) * F_];
    const float w1 = wcol[(size_t)(jq * 4 + 1) * F_];
    const float w2 = wcol[(size_t)(jq * 4 + 2) * F_];
    const float w3 = wcol[(size_t)(jq * 4 + 3) * F_];
    ss += w0 * u4.x + w1 * u4.y + w2 * u4.z + w3 * u4.w;
    qq += w0 * p4.x + w1 * p4.y + w2 * p4.z + w3 * p4.w;
  }
  ps[((size_t)b * NCH + cx) * F_ + tid] = ss;
  pq[((size_t)b * NCH + cx) * F_ + tid] = qq;
}

// ---------------------------------------------------------------------------
// k2_fused<NCH>: grid B. Fold partials, sigmoid, final reduce.
template <int NCH>
__global__ __launch_bounds__(256) void k2_fused(
    const float* __restrict__ bc, const float* __restrict__ hidden,
    const float* __restrict__ wsSw, const float* __restrict__ wsrh,
    const float* __restrict__ wssc,
    const float* __restrict__ ps, const float* __restrict__ pq,
    float* __restrict__ out) {
  const int b = blockIdx.x;
  const int x = threadIdx.x;
  const int lane = x & 63;
  const int wid = x >> 6;
  __shared__ float red[4];

  float s = 0.f, q = 0.f;
#pragma unroll
  for (int cx = 0; cx < NCH; ++cx) {
    s += ps[((size_t)b * NCH + cx) * F_ + x];
    q += pq[((size_t)b * NCH + cx) * F_ + x];
  }
  const float R  = wssc[0];
  const float c0 = wssc[1];
  const float bcx = bc[x];
  s += bcx * wsSw[b];
  const float a = 1.f / (1.f + expf(-s));
  float partial = a * (q + bcx * R) + wsrh[x] * hidden[(size_t)b * I_ + x];
#pragma unroll
  for (int m = 32; m >= 1; m >>= 1) partial += __shfl_xor(partial, m, 64);
  if (lane == 0) red[wid] = partial;
  __syncthreads();
  if (x == 0) out[b] = red[0] + red[1] + red[2] + red[3] + c0;
}

// ---------------------------------------------------------------------------
// Classic fallback (byte-identical R5 k1/k2) for small ws_size.
__global__ __launch_bounds__(256) void k1_scan(
    const float* __restrict__ inp, const float* __restrict__ wsw,
    const float* __restrict__ wsrp,
    float* __restrict__ wsu, float* __restrict__ wsp) {
  const int ROWS = 32;
  const int b = blockIdx.y;
  const int t0 = blockIdx.x * ROWS;
  const int tid = threadIdx.x;
  const int lane = tid & 63;
  const int wid = tid >> 6;

  __shared__ float rv_lds[F_];
  float rv = 0.f;
#pragma unroll
  for (int g = 0; g < NG; ++g) rv += wsrp[g * 512 + 256 + tid];
  rv_lds[tid] = rv;
  __syncthreads();

  const float4 w4  = ((const float4*)(wsw + (size_t)b * F_))[lane];
  const float4 rv4 = ((const float4*)rv_lds)[lane];
  const float* base = inp + ((size_t)b * S_ + t0) * I_;
  float* uo = wsu + (size_t)b * S_ + t0;
  float* po = wsp + (size_t)b * S_ + t0;

#pragma unroll
  for (int rr = 0; rr < ROWS / 4; ++rr) {
    const int row = wid + 4 * rr;
    const float4 in4 = ((const float4*)(base + (size_t)row * I_))[lane];
    float du = in4.x * w4.x + in4.y * w4.y + in4.z * w4.z + in4.w * w4.w;
    float dp = in4.x * rv4.x + in4.y * rv4.y + in4.z * rv4.z + in4.w * rv4.w;
#pragma unroll
    for (int m = 32; m >= 1; m >>= 1) {
      du += __shfl_xor(du, m, 64);
      dp += __shfl_xor(dp, m, 64);
    }
    if (lane == 0) { uo[row] = du; po[row] = dp; }
  }
}

__global__ __launch_bounds__(256) void k2_epilogue(
    const float* __restrict__ Wc, const float* __restrict__ bc,
    const float* __restrict__ b2, const float* __restrict__ Wfc,
    const float* __restrict__ bfc, const float* __restrict__ hidden,
    const float* __restrict__ wsu, const float* __restrict__ wsp,
    const float* __restrict__ wsSw, const float* __restrict__ wsrp,
    float* __restrict__ out) {
  const int b0 = blockIdx.x * 4;
  const int tid = threadIdx.x;
  const int lane = tid & 63;
  const int wid = tid >> 6;
  __shared__ float u[4][S_];
  __shared__ float p[4][S_];
  __shared__ float redA[4], redB[4];
  __shared__ float wred[4][4];

  float rh = 0.f, rv = 0.f;
#pragma unroll
  for (int g = 0; g < NG; ++g) {
    rh += wsrp[g * 512 + tid];
    rv += wsrp[g * 512 + 256 + tid];
  }
  float t0 = rv, t1 = Wfc[tid] * b2[tid];
#pragma unroll
  for (int m = 32; m >= 1; m >>= 1) {
    t0 += __shfl_xor(t0, m, 64);
    t1 += __shfl_xor(t1, m, 64);
  }
  if (lane == 0) { redA[wid] = t0; redB[wid] = t1; }

#pragma unroll
  for (int k = 0; k < 4; ++k) {
    u[k][tid]       = wsu[(size_t)(b0 + k) * S_ + tid];
    u[k][tid + 256] = wsu[(size_t)(b0 + k) * S_ + tid + 256];
    p[k][tid]       = wsp[(size_t)(b0 + k) * S_ + tid];
    p[k][tid + 256] = wsp[(size_t)(b0 + k) * S_ + tid + 256];
  }
  __syncthreads();

  const float R  = redA[0] + redA[1] + redA[2] + redA[3];
  const float c0 = redB[0] + redB[1] + redB[2] + redB[3] + bfc[0];

  const int x = tid;
  const float4* wrow = (const float4*)(Wc + (size_t)x * S_);
  float ss[4] = {0.f, 0.f, 0.f, 0.f};
  float qs[4] = {0.f, 0.f, 0.f, 0.f};
#pragma unroll 4
  for (int tq = 0; tq < S_ / 4; ++tq) {
    const float4 v = wrow[tq];
    const int t = 4 * tq;
#pragma unroll
    for (int k = 0; k < 4; ++k) {
      ss[k] += v.x * u[k][t] + v.y * u[k][t + 1] + v.z * u[k][t + 2] + v.w * u[k][t + 3];
      qs[k] += v.x * p[k][t] + v.y * p[k][t + 1] + v.z * p[k][t + 2] + v.w * p[k][t + 3];
    }
  }

  const float bcx = bc[x];
#pragma unroll
  for (int k = 0; k < 4; ++k) {
    const float Sw = wsSw[b0 + k];
    const float s = ss[k] + bcx * Sw;
    const float a = 1.f / (1.f + expf(-s));
    float partial = a * (qs[k] + bcx * R) + rh * hidden[(size_t)(b0 + k) * I_ + x];
#pragma unroll
    for (int m = 32; m >= 1; m >>= 1) partial += __shfl_xor(partial, m, 64);
    if (lane == 0) wred[k][wid] = partial;
  }
  __syncthreads();
  if (tid < 4)
    out[b0 + tid] = wred[tid][0] + wred[tid][1] + wred[tid][2] + wred[tid][3] + c0;
}

// ---------------------------------------------------------------------------
extern "C" void kernel_launch(void* const* d_in, const int* in_sizes, int n_in,
                              void* d_out, int out_size, void* d_ws, size_t ws_size,
                              hipStream_t stream) {
  (void)in_sizes; (void)n_in; (void)out_size;
  const float* hidden = (const float*)d_in[0];
  const float* inp    = (const float*)d_in[1];
  const float* W1     = (const float*)d_in[2];
  const float* Wc     = (const float*)d_in[3];
  const float* bc     = (const float*)d_in[4];
  const float* W2     = (const float*)d_in[5];
  const float* b2     = (const float*)d_in[6];
  const float* Wfc    = (const float*)d_in[7];
  const float* bfc    = (const float*)d_in[8];
  float* out = (float*)d_out;
  float* ws  = (float*)d_ws;

  hipLaunchKernelGGL(k_pre, dim3(B_ / 4 + NG + 32), dim3(256), 0, stream,
                     hidden, W1, W2, Wfc, Wc, ws);
  hipLaunchKernelGGL(k_mid, dim3(1), dim3(256), 0, stream, Wfc, b2, bfc, ws);

  const size_t need8 = ((size_t)OFF_PS + 2ull * B_ * 8 * F_) * 4;
  const size_t need4 = ((size_t)OFF_PS + 2ull * B_ * 4 * F_) * 4;

  if (ws_size >= need8) {
    float* ps = ws + OFF_PS;
    float* pq = ps + (size_t)B_ * 8 * F_;
    hipLaunchKernelGGL(HIP_KERNEL_NAME(k1_fused<8>), dim3(8, B_), dim3(256), 0, stream,
                       inp, ws + OFF_W, ws + OFF_RV, ws + OFF_WCT, ps, pq);
    hipLaunchKernelGGL(HIP_KERNEL_NAME(k2_fused<8>), dim3(B_), dim3(256), 0, stream,
                       bc, hidden, ws + OFF_SW, ws + OFF_RH, ws + OFF_SC, ps, pq, out);
  } else if (ws_size >= need4) {
    float* ps = ws + OFF_PS;
    float* pq = ps + (size_t)B_ * 4 * F_;
    hipLaunchKernelGGL(HIP_KERNEL_NAME(k1_fused<4>), dim3(4, B_), dim3(256), 0, stream,
                       inp, ws + OFF_W, ws + OFF_RV, ws + OFF_WCT, ps, pq);
    hipLaunchKernelGGL(HIP_KERNEL_NAME(k2_fused<4>), dim3(B_), dim3(256), 0, stream,
                       bc, hidden, ws + OFF_SW, ws + OFF_RH, ws + OFF_SC, ps, pq, out);
  } else {
    hipLaunchKernelGGL(k1_scan, dim3(S_ / 32, B_), dim3(256), 0, stream,
                       inp, ws + OFF_W, ws + OFF_RP, ws + OFF_U2, ws + OFF_P2);
    hipLaunchKernelGGL(k2_epilogue, dim3(B_ / 4), dim3(256), 0, stream,
                       Wc, bc, b2, Wfc, bfc, hidden,
                       ws + OFF_U2, ws + OFF_P2, ws + OFF_SW, ws + OFF_RP, out);
  }
}